// Round 1
// baseline (2260.611 us; speedup 1.0000x reference)
//
#include <hip/hip_runtime.h>
#include <math.h>

#ifndef M_PI
#define M_PI 3.14159265358979323846
#endif

#define HW 16384

// ---------- swizzled LDS addressing for 128x128 f32 plane tiles ----------
// logical (r,c) -> physical r*128 + 4*((c>>2) ^ ((r>>3)&7)) + (c&3)
__device__ __forceinline__ int swz4(int r, int c4) {
  return (r << 7) + ((((c4 >> 2) ^ ((r >> 3) & 7)) << 2));
}

// ---------- tables: cosine map (H==W==128) and decay exponent ----------
__global__ void k0_tables(float* __restrict__ cc, float* __restrict__ ee) {
  int gid = blockIdx.x * 256 + threadIdx.x;   // 16384
  int n = gid >> 7, m = gid & 127;
  double v = cos((double)n * ((double)m + 0.5) * (M_PI / 128.0)) * sqrt(2.0 / 128.0);
  if (n == 0) v *= 0.70710678118654752440;
  cc[gid] = (float)v;
  double wn = (double)n * (M_PI / 128.0), wm = (double)m * (M_PI / 128.0);
  ee[gid] = (float)(wn * wn + wm * wm);
}

// ---------- generic weight transpose: src[D][C] -> dst[C][D] ----------
__global__ void k_wt(const float* __restrict__ src, float* __restrict__ dst, int D, int C) {
  int gid = blockIdx.x * 256 + threadIdx.x;
  if (gid >= D * C) return;
  int d = gid / C, c = gid % C;
  dst[c * D + d] = src[gid];
}

// ---------- K2: fused depthwise 3x3 conv + lin GEMM (K=96 -> N=192 split) ----------
__global__ __launch_bounds__(256) void k2_conv_lin(
    const float* __restrict__ x, const float* __restrict__ dw_w,
    const float* __restrict__ dw_b, const float* __restrict__ linT,
    const float* __restrict__ lin_b, float* __restrict__ x1p, float* __restrict__ z) {
  int gid = blockIdx.x * 256 + threadIdx.x;   // 131072 = B*HW
  int b = gid >> 14, hw = gid & 16383;
  int h = hw >> 7, w = hw & 127;
  const float* xb = x + (size_t)b * 96 * HW + hw;
  const bool tp = h > 0, bt = h < 127, lf = w > 0, rt = w < 127;

  for (int half = 0; half < 2; ++half) {
    float acc[96];
#pragma unroll
    for (int d = 0; d < 96; ++d) acc[d] = lin_b[half * 96 + d];
    for (int c = 0; c < 96; ++c) {
      const float* p = xb + (size_t)c * HW;
      float v   = p[0];
      float vl  = lf ? p[-1] : 0.f;
      float vr  = rt ? p[1] : 0.f;
      float vt  = tp ? p[-128] : 0.f;
      float vb  = bt ? p[128] : 0.f;
      float vtl = (tp && lf) ? p[-129] : 0.f;
      float vtr = (tp && rt) ? p[-127] : 0.f;
      float vbl = (bt && lf) ? p[127] : 0.f;
      float vbr = (bt && rt) ? p[129] : 0.f;
      const float* wc = dw_w + c * 9;
      float conv = vtl * wc[0] + vt * wc[1] + vtr * wc[2]
                 + vl  * wc[3] + v  * wc[4] + vr  * wc[5]
                 + vbl * wc[6] + vb * wc[7] + vbr * wc[8] + dw_b[c];
      const float* wr = linT + c * 192 + half * 96;
#pragma unroll
      for (int d = 0; d < 96; ++d) acc[d] = fmaf(conv, wr[d], acc[d]);
    }
    if (half == 0) {
#pragma unroll
      for (int d = 0; d < 96; ++d) x1p[(size_t)(b * 96 + d) * HW + hw] = acc[d];
    } else {
      float* zp = z + (size_t)gid * 96;
#pragma unroll
      for (int d = 0; d < 96; d += 4)
        *(float4*)&zp[d] = make_float4(acc[d], acc[d + 1], acc[d + 2], acc[d + 3]);
    }
  }
}

// ---------- K3: outline_feat transpose to plane-major + mean over B ----------
__global__ __launch_bounds__(256) void k3_transpose_mean(
    const float* __restrict__ of, float* __restrict__ ofp, float* __restrict__ cmU) {
  __shared__ float tile[64 * 97];
  int hw0 = blockIdx.x * 64;
  int tid = threadIdx.x;
  float sum[24];
#pragma unroll
  for (int t = 0; t < 24; ++t) sum[t] = 0.f;
  for (int b = 0; b < 8; ++b) {
    __syncthreads();
#pragma unroll
    for (int t = 0; t < 24; ++t) {
      int l = tid + t * 256;
      int r = l / 96, c0 = l % 96;
      tile[r * 97 + c0] = of[((size_t)b * 16384 + hw0 + r) * 96 + c0];
    }
    __syncthreads();
#pragma unroll
    for (int t = 0; t < 24; ++t) {
      int l = tid + t * 256;
      int c0 = l >> 6, r = l & 63;
      float v = tile[r * 97 + c0];
      sum[t] += v;
      ofp[(size_t)(b * 96 + c0) * HW + hw0 + r] = v;
    }
  }
#pragma unroll
  for (int t = 0; t < 24; ++t) {
    int l = tid + t * 256;
    int c0 = l >> 6, r = l & 63;
    cmU[(size_t)c0 * HW + hw0 + r] = sum[t] * 0.125f;
  }
}

// ---------- K3b: k = relu((freq+otm)@k_w^T + k_b); P1 = exp(-e*k) ----------
__global__ __launch_bounds__(256) void k3b_kgemm(
    const float* __restrict__ fe, const float* __restrict__ otm,
    const float* __restrict__ kT, const float* __restrict__ kb,
    const float* __restrict__ ee, float* __restrict__ P1) {
  int row = blockIdx.x * 256 + threadIdx.x;
  float acc[96];
#pragma unroll
  for (int d = 0; d < 96; ++d) acc[d] = kb[d];
  for (int c = 0; c < 96; ++c) {
    float a = fe[(size_t)row * 96 + c] + otm[(size_t)c * HW + row];
    const float* wr = kT + c * 96;
#pragma unroll
    for (int d = 0; d < 96; ++d) acc[d] = fmaf(a, wr[d], acc[d]);
  }
  float er = ee[row];
#pragma unroll
  for (int d = 0; d < 96; ++d)
    P1[(size_t)d * HW + row] = expf(-er * fmaxf(acc[d], 0.f));
}

// ---------- fused per-plane heat pass: Y = Cc^T ( P . (Cc U Cc^T) ) Cc ----------
// Primitive computes OUT[i][j] = sum_k A[k][i] * B[k][j] (all row-reads).
template <bool A_PANEL, bool PANEL_T, bool OUT_T>
__device__ __forceinline__ void mm_step(const float* __restrict__ cc,
                                        const float* __restrict__ Afull,
                                        const float* __restrict__ Bfull,
                                        float* Pan, float* OUT, int tid) {
  const int ty = tid >> 4, tx = tid & 15;
  const int i0 = ty << 3, j0 = tx << 3;
  float acc[8][8];
#pragma unroll
  for (int i = 0; i < 8; ++i)
#pragma unroll
    for (int j = 0; j < 8; ++j) acc[i][j] = 0.f;

  for (int k0 = 0; k0 < 128; k0 += 16) {
    __syncthreads();
    if constexpr (PANEL_T) {   // Pan[kk][x] = cc[x][k0+kk]
#pragma unroll
      for (int rep = 0; rep < 2; ++rep) {
        int xx = (tid >> 2) + rep * 64;
        int kk4 = (tid & 3) << 2;
        float4 v = *(const float4*)&cc[xx * 128 + k0 + kk4];
        Pan[(kk4 + 0) * 132 + xx] = v.x;
        Pan[(kk4 + 1) * 132 + xx] = v.y;
        Pan[(kk4 + 2) * 132 + xx] = v.z;
        Pan[(kk4 + 3) * 132 + xx] = v.w;
      }
    } else {                   // Pan[kk][x] = cc[k0+kk][x]
#pragma unroll
      for (int rep = 0; rep < 2; ++rep) {
        int q = tid + rep * 256;
        int kk = q >> 5, c4 = (q & 31) << 2;
        *(float4*)&Pan[kk * 132 + c4] = *(const float4*)&cc[(k0 + kk) * 128 + c4];
      }
    }
    __syncthreads();
#pragma unroll
    for (int kk = 0; kk < 16; ++kk) {
      const int k = k0 + kk;
      float a[8], bv[8];
      if constexpr (A_PANEL) {
        *(float4*)&a[0] = *(const float4*)&Pan[kk * 132 + i0];
        *(float4*)&a[4] = *(const float4*)&Pan[kk * 132 + i0 + 4];
        *(float4*)&bv[0] = *(const float4*)&Bfull[swz4(k, j0)];
        *(float4*)&bv[4] = *(const float4*)&Bfull[swz4(k, j0 + 4)];
      } else {
        *(float4*)&a[0] = *(const float4*)&Afull[swz4(k, i0)];
        *(float4*)&a[4] = *(const float4*)&Afull[swz4(k, i0 + 4)];
        *(float4*)&bv[0] = *(const float4*)&Pan[kk * 132 + j0];
        *(float4*)&bv[4] = *(const float4*)&Pan[kk * 132 + j0 + 4];
      }
#pragma unroll
      for (int i = 0; i < 8; ++i)
#pragma unroll
        for (int j = 0; j < 8; ++j) acc[i][j] = fmaf(a[i], bv[j], acc[i][j]);
    }
  }
  if constexpr (OUT_T) {
#pragma unroll
    for (int j = 0; j < 8; ++j) {
      *(float4*)&OUT[swz4(j0 + j, i0)] =
          make_float4(acc[0][j], acc[1][j], acc[2][j], acc[3][j]);
      *(float4*)&OUT[swz4(j0 + j, i0 + 4)] =
          make_float4(acc[4][j], acc[5][j], acc[6][j], acc[7][j]);
    }
  } else {
#pragma unroll
    for (int i = 0; i < 8; ++i) {
      *(float4*)&OUT[swz4(i0 + i, j0)] =
          make_float4(acc[i][0], acc[i][1], acc[i][2], acc[i][3]);
      *(float4*)&OUT[swz4(i0 + i, j0 + 4)] =
          make_float4(acc[i][4], acc[i][5], acc[i][6], acc[i][7]);
    }
  }
}

__global__ __launch_bounds__(256) void heat_kernel(
    float* bufA, float* bufB, const float* __restrict__ P,
    const float* __restrict__ cc, int Ceff) {
  __shared__ float Xs[128 * 128];
  __shared__ float Ys[128 * 128];
  __shared__ float Pan[16 * 132];
  int tid = threadIdx.x;
  int plane = blockIdx.x;
  int b = plane / Ceff, c = plane % Ceff;
  float* Ug = (c < 96) ? (bufA + (size_t)(b * 96 + c) * HW)
                       : (bufB + (size_t)(b * 96 + (c - 96)) * HW);
  const float* Pp = P + (size_t)c * HW;

#pragma unroll
  for (int t = 0; t < 16; ++t) {           // load U (swizzled into Xs)
    int q = tid + t * 256;                 // float4 index, 4096 total
    int r = q >> 5, c4 = (q & 31) << 2;
    *(float4*)&Xs[swz4(r, c4)] = *(const float4*)&Ug[(r << 7) + c4];
  }
  // step1: T = Cc*U        (A = panelT, B = Xs)  -> Ys holds T^T
  mm_step<true, true, true>(cc, nullptr, Xs, Pan, Ys, tid);
  // step2: S = T*Cc^T      (A = Ys(T^T), B = panelT) -> Xs holds S
  mm_step<false, true, false>(cc, Ys, nullptr, Pan, Xs, tid);
  __syncthreads();
#pragma unroll
  for (int t = 0; t < 64; ++t) {           // decay multiply S *= P
    int q = tid + t * 256;
    int r = q >> 7, cx = q & 127;
    int idx = (r << 7) + (((((cx >> 2) ^ ((r >> 3) & 7)) << 2)) | (cx & 3));
    Xs[idx] *= Pp[q];
  }
  // step3: T2 = Cc^T*S     (A = panelR, B = Xs) -> Ys holds T2^T
  mm_step<true, false, true>(cc, nullptr, Xs, Pan, Ys, tid);
  // step4: Y = T2*Cc       (A = Ys(T2^T), B = panelR) -> Xs holds Y
  mm_step<false, false, false>(cc, Ys, nullptr, Pan, Xs, tid);
  __syncthreads();
#pragma unroll
  for (int t = 0; t < 16; ++t) {           // store in place
    int q = tid + t * 256;
    int r = q >> 5, c4 = (q & 31) << 2;
    *(float4*)&Ug[(r << 7) + c4] = *(float4*)&Xs[swz4(r, c4)];
  }
}

// ---------- K5: catmean lower half = mean_b(y1) ----------
__global__ void k5_mean(const float* __restrict__ x1p, float* __restrict__ cmL) {
  int idx = blockIdx.x * 256 + threadIdx.x;   // < 96*HW, layout [c][s]
  int c = idx >> 14, s = idx & 16383;
  float sum = 0.f;
#pragma unroll
  for (int b = 0; b < 8; ++b) sum += x1p[(size_t)(b * 96 + c) * HW + s];
  cmL[idx] = sum * 0.125f;
}

// ---------- K6: skfeat = catmean @ lin2_w^T + lin2_b (c-major in/out) ----------
__global__ __launch_bounds__(256) void k6_skf(
    const float* __restrict__ cm, const float* __restrict__ w2T,
    const float* __restrict__ b2, float* __restrict__ skf) {
  int row = blockIdx.x * 256 + threadIdx.x;
  for (int half = 0; half < 2; ++half) {
    float acc[96];
#pragma unroll
    for (int d = 0; d < 96; ++d) acc[d] = b2[half * 96 + d];
    for (int k = 0; k < 192; ++k) {
      float a = cm[(size_t)k * HW + row];
      const float* wr = w2T + k * 192 + half * 96;
#pragma unroll
      for (int d = 0; d < 96; ++d) acc[d] = fmaf(a, wr[d], acc[d]);
    }
#pragma unroll
    for (int d = 0; d < 96; ++d) skf[(size_t)(half * 96 + d) * HW + row] = acc[d];
  }
}

// ---------- K7: k2 = relu(skf@k2_w^T + k2_b); P2 = exp(-e*k2) ----------
__global__ __launch_bounds__(256) void k7_k2(
    const float* __restrict__ skf, const float* __restrict__ w2T,
    const float* __restrict__ b2, const float* __restrict__ ee,
    float* __restrict__ P2) {
  int row = blockIdx.x * 256 + threadIdx.x;
  float er = ee[row];
  for (int half = 0; half < 2; ++half) {
    float acc[96];
#pragma unroll
    for (int d = 0; d < 96; ++d) acc[d] = b2[half * 96 + d];
    for (int k = 0; k < 192; ++k) {
      float a = skf[(size_t)k * HW + row];
      const float* wr = w2T + k * 192 + half * 96;
#pragma unroll
      for (int d = 0; d < 96; ++d) acc[d] = fmaf(a, wr[d], acc[d]);
    }
#pragma unroll
    for (int d = 0; d < 96; ++d)
      P2[(size_t)(half * 96 + d) * HW + row] = expf(-er * fmaxf(acc[d], 0.f));
  }
}

// ---------- K9: lin3 + LayerNorm + *silu(z) + out GEMM + NCHW write ----------
__global__ __launch_bounds__(256) void k9_epilogue(
    const float* __restrict__ y1, const float* __restrict__ y2,
    const float* __restrict__ z,
    const float* __restrict__ lin3T, const float* __restrict__ lin3b,
    const float* __restrict__ lng, const float* __restrict__ lnb,
    const float* __restrict__ outT, const float* __restrict__ outb,
    float* __restrict__ out) {
  int gid = blockIdx.x * 256 + threadIdx.x;
  int b = gid >> 14, hw = gid & 16383;
  float t[96];
#pragma unroll
  for (int d = 0; d < 96; ++d) t[d] = lin3b[d];
  for (int k = 0; k < 96; ++k) {
    float a = y1[(size_t)(b * 96 + k) * HW + hw];
    const float* wr = lin3T + k * 96;
#pragma unroll
    for (int d = 0; d < 96; ++d) t[d] = fmaf(a, wr[d], t[d]);
  }
  for (int k = 0; k < 96; ++k) {
    float a = y2[(size_t)(b * 96 + k) * HW + hw];
    const float* wr = lin3T + (96 + k) * 96;
#pragma unroll
    for (int d = 0; d < 96; ++d) t[d] = fmaf(a, wr[d], t[d]);
  }
  float mu = 0.f;
#pragma unroll
  for (int d = 0; d < 96; ++d) mu += t[d];
  mu *= (1.f / 96.f);
  float var = 0.f;
#pragma unroll
  for (int d = 0; d < 96; ++d) { float dv = t[d] - mu; var = fmaf(dv, dv, var); }
  var *= (1.f / 96.f);
  float inv = rsqrtf(var + 1e-5f);
  const float* zp = z + (size_t)gid * 96;
#pragma unroll
  for (int d = 0; d < 96; ++d) {
    float zv = zp[d];
    float sil = zv / (1.f + expf(-zv));
    t[d] = ((t[d] - mu) * inv * lng[d] + lnb[d]) * sil;
  }
  for (int half = 0; half < 2; ++half) {
    float acc[48];
#pragma unroll
    for (int j = 0; j < 48; ++j) acc[j] = outb[half * 48 + j];
#pragma unroll
    for (int c2 = 0; c2 < 96; ++c2) {
      float a = t[c2];
      const float* wr = outT + c2 * 96 + half * 48;
#pragma unroll
      for (int j = 0; j < 48; ++j) acc[j] = fmaf(a, wr[j], acc[j]);
    }
#pragma unroll
    for (int j = 0; j < 48; ++j)
      out[(size_t)(b * 96 + half * 48 + j) * HW + hw] = acc[j];
  }
}

extern "C" void kernel_launch(void* const* d_in, const int* in_sizes, int n_in,
                              void* d_out, int out_size, void* d_ws, size_t ws_size,
                              hipStream_t stream) {
  const float* x      = (const float*)d_in[0];
  const float* fe     = (const float*)d_in[1];
  const float* of     = (const float*)d_in[2];
  const float* dw_w   = (const float*)d_in[3];
  const float* dw_b   = (const float*)d_in[4];
  const float* lin_w  = (const float*)d_in[5];
  const float* lin_b  = (const float*)d_in[6];
  const float* k_w    = (const float*)d_in[7];
  const float* k_b    = (const float*)d_in[8];
  const float* lin2_w = (const float*)d_in[9];
  const float* lin2_b = (const float*)d_in[10];
  const float* k2_w   = (const float*)d_in[11];
  const float* k2_b   = (const float*)d_in[12];
  const float* lin3_w = (const float*)d_in[13];
  const float* lin3_b = (const float*)d_in[14];
  const float* ln_g   = (const float*)d_in[15];
  const float* ln_b   = (const float*)d_in[16];
  const float* out_w  = (const float*)d_in[17];
  const float* out_b  = (const float*)d_in[18];
  float* out = (float*)d_out;

  float* ws    = (float*)d_ws;
  float* x1p   = ws;                      // [B][96][HW]  (x1 -> y1 -> y2 low)
  float* z     = x1p   + 12582912;        // [B][HW][96]
  float* ofp   = z     + 12582912;        // [B][96][HW]  (outline planes -> y2 high)
  float* cm    = ofp   + 12582912;        // [192][HW] catmean (c-major)
  float* skf   = cm    + 3145728;         // [192][HW]
  float* P1    = skf   + 3145728;         // [96][HW]
  float* P2    = P1    + 1572864;         // [192][HW]
  float* cc    = P2    + 3145728;         // [128][128]
  float* ee    = cc    + 16384;           // [128][128]
  float* linT  = ee    + 16384;           // [96][192]
  float* kT    = linT  + 18432;           // [96][96]
  float* lin2T = kT    + 9216;            // [192][192]
  float* k2T   = lin2T + 36864;           // [192][192]
  float* lin3T = k2T   + 36864;           // [192][96]
  float* outT  = lin3T + 18432;           // [96][96]
  (void)in_sizes; (void)n_in; (void)out_size; (void)ws_size;

  k0_tables<<<64, 256, 0, stream>>>(cc, ee);
  k_wt<<<72, 256, 0, stream>>>(lin_w, linT, 192, 96);
  k_wt<<<36, 256, 0, stream>>>(k_w, kT, 96, 96);
  k_wt<<<144, 256, 0, stream>>>(lin2_w, lin2T, 192, 192);
  k_wt<<<144, 256, 0, stream>>>(k2_w, k2T, 192, 192);
  k_wt<<<72, 256, 0, stream>>>(lin3_w, lin3T, 96, 192);
  k_wt<<<36, 256, 0, stream>>>(out_w, outT, 96, 96);

  k2_conv_lin<<<512, 256, 0, stream>>>(x, dw_w, dw_b, linT, lin_b, x1p, z);
  k3_transpose_mean<<<256, 256, 0, stream>>>(of, ofp, cm + (size_t)96 * HW);
  k3b_kgemm<<<64, 256, 0, stream>>>(fe, cm + (size_t)96 * HW, kT, k_b, ee, P1);
  heat_kernel<<<768, 256, 0, stream>>>(x1p, x1p, P1, cc, 96);
  k5_mean<<<6144, 256, 0, stream>>>(x1p, cm);
  k6_skf<<<64, 256, 0, stream>>>(cm, lin2T, lin2_b, skf);
  k7_k2<<<64, 256, 0, stream>>>(skf, k2T, k2_b, ee, P2);
  heat_kernel<<<1536, 256, 0, stream>>>(x1p, ofp, P2, cc, 192);
  k9_epilogue<<<512, 256, 0, stream>>>(x1p, ofp, z, lin3T, lin3_b, ln_g, ln_b,
                                       outT, out_b, out);
}

// Round 2
// 2127.023 us; speedup vs baseline: 1.0628x; 1.0628x over previous
//
#include <hip/hip_runtime.h>
#include <math.h>

#ifndef M_PI
#define M_PI 3.14159265358979323846
#endif

#define HW 16384

// ---------- swizzled LDS addressing for 128x128 f32 plane tiles ----------
// logical (r,c) -> physical r*128 + 4*((c>>2) ^ ((r>>3)&7)) + (c&3)
__device__ __forceinline__ int swz4(int r, int c4) {
  return (r << 7) + ((((c4 >> 2) ^ ((r >> 3) & 7)) << 2));
}

// ---------- tables: cosine map (H==W==128) and decay exponent ----------
__global__ void k0_tables(float* __restrict__ cc, float* __restrict__ ee) {
  int gid = blockIdx.x * 256 + threadIdx.x;   // 16384
  int n = gid >> 7, m = gid & 127;
  double v = cos((double)n * ((double)m + 0.5) * (M_PI / 128.0)) * sqrt(2.0 / 128.0);
  if (n == 0) v *= 0.70710678118654752440;
  cc[gid] = (float)v;
  double wn = (double)n * (M_PI / 128.0), wm = (double)m * (M_PI / 128.0);
  ee[gid] = (float)(wn * wn + wm * wm);
}

// ---------- generic weight transpose: src[D][C] -> dst[C][D] ----------
__global__ void k_wt(const float* __restrict__ src, float* __restrict__ dst, int D, int C) {
  int gid = blockIdx.x * 256 + threadIdx.x;
  if (gid >= D * C) return;
  int d = gid / C, c = gid % C;
  dst[c * D + d] = src[gid];
}

// ---------- K2: fused depthwise 3x3 conv + lin GEMM (K=96 -> N=192 split) ----------
__global__ __launch_bounds__(256) void k2_conv_lin(
    const float* __restrict__ x, const float* __restrict__ dw_w,
    const float* __restrict__ dw_b, const float* __restrict__ linT,
    const float* __restrict__ lin_b, float* __restrict__ x1p, float* __restrict__ z) {
  int gid = blockIdx.x * 256 + threadIdx.x;   // 131072 = B*HW
  int b = gid >> 14, hw = gid & 16383;
  int h = hw >> 7, w = hw & 127;
  const float* xb = x + (size_t)b * 96 * HW + hw;
  const bool tp = h > 0, bt = h < 127, lf = w > 0, rt = w < 127;

  for (int half = 0; half < 2; ++half) {
    float acc[96];
#pragma unroll
    for (int d = 0; d < 96; ++d) acc[d] = lin_b[half * 96 + d];
    for (int c = 0; c < 96; ++c) {
      const float* p = xb + (size_t)c * HW;
      float v   = p[0];
      float vl  = lf ? p[-1] : 0.f;
      float vr  = rt ? p[1] : 0.f;
      float vt  = tp ? p[-128] : 0.f;
      float vb  = bt ? p[128] : 0.f;
      float vtl = (tp && lf) ? p[-129] : 0.f;
      float vtr = (tp && rt) ? p[-127] : 0.f;
      float vbl = (bt && lf) ? p[127] : 0.f;
      float vbr = (bt && rt) ? p[129] : 0.f;
      const float* wc = dw_w + c * 9;
      float conv = vtl * wc[0] + vt * wc[1] + vtr * wc[2]
                 + vl  * wc[3] + v  * wc[4] + vr  * wc[5]
                 + vbl * wc[6] + vb * wc[7] + vbr * wc[8] + dw_b[c];
      const float* wr = linT + c * 192 + half * 96;
#pragma unroll
      for (int d = 0; d < 96; ++d) acc[d] = fmaf(conv, wr[d], acc[d]);
    }
    if (half == 0) {
#pragma unroll
      for (int d = 0; d < 96; ++d) x1p[(size_t)(b * 96 + d) * HW + hw] = acc[d];
    } else {
      float* zp = z + (size_t)gid * 96;
#pragma unroll
      for (int d = 0; d < 96; d += 4)
        *(float4*)&zp[d] = make_float4(acc[d], acc[d + 1], acc[d + 2], acc[d + 3]);
    }
  }
}

// ---------- K3: outline_feat transpose to plane-major + mean over B ----------
__global__ __launch_bounds__(256) void k3_transpose_mean(
    const float* __restrict__ of, float* __restrict__ ofp, float* __restrict__ cmU) {
  __shared__ float tile[64 * 97];
  int hw0 = blockIdx.x * 64;
  int tid = threadIdx.x;
  float sum[24];
#pragma unroll
  for (int t = 0; t < 24; ++t) sum[t] = 0.f;
  for (int b = 0; b < 8; ++b) {
    __syncthreads();
#pragma unroll
    for (int t = 0; t < 24; ++t) {
      int l = tid + t * 256;
      int r = l / 96, c0 = l % 96;
      tile[r * 97 + c0] = of[((size_t)b * 16384 + hw0 + r) * 96 + c0];
    }
    __syncthreads();
#pragma unroll
    for (int t = 0; t < 24; ++t) {
      int l = tid + t * 256;
      int c0 = l >> 6, r = l & 63;
      float v = tile[r * 97 + c0];
      sum[t] += v;
      ofp[(size_t)(b * 96 + c0) * HW + hw0 + r] = v;
    }
  }
#pragma unroll
  for (int t = 0; t < 24; ++t) {
    int l = tid + t * 256;
    int c0 = l >> 6, r = l & 63;
    cmU[(size_t)c0 * HW + hw0 + r] = sum[t] * 0.125f;
  }
}

// ---------- K3b: k = relu((freq+otm)@k_w^T + k_b); P1 = exp(-e*k) ----------
__global__ __launch_bounds__(256) void k3b_kgemm(
    const float* __restrict__ fe, const float* __restrict__ otm,
    const float* __restrict__ kT, const float* __restrict__ kb,
    const float* __restrict__ ee, float* __restrict__ P1) {
  int row = blockIdx.x * 256 + threadIdx.x;
  float acc[96];
#pragma unroll
  for (int d = 0; d < 96; ++d) acc[d] = kb[d];
  for (int c = 0; c < 96; ++c) {
    float a = fe[(size_t)row * 96 + c] + otm[(size_t)c * HW + row];
    const float* wr = kT + c * 96;
#pragma unroll
    for (int d = 0; d < 96; ++d) acc[d] = fmaf(a, wr[d], acc[d]);
  }
  float er = ee[row];
#pragma unroll
  for (int d = 0; d < 96; ++d)
    P1[(size_t)d * HW + row] = expf(-er * fmaxf(acc[d], 0.f));
}

// ---------- fused per-plane heat pass: Y = Cc^T ( P . (Cc U Cc^T) ) Cc ----------
// Primitive computes OUT[i][j] = sum_k A[k][i] * B[k][j] (all row-reads).
template <bool A_PANEL, bool PANEL_T, bool OUT_T>
__device__ __forceinline__ void mm_step(const float* __restrict__ cc,
                                        const float* __restrict__ Afull,
                                        const float* __restrict__ Bfull,
                                        float* Pan, float* OUT, int tid) {
  const int ty = tid >> 4, tx = tid & 15;
  const int i0 = ty << 3, j0 = tx << 3;
  float acc[8][8];
#pragma unroll
  for (int i = 0; i < 8; ++i)
#pragma unroll
    for (int j = 0; j < 8; ++j) acc[i][j] = 0.f;

  for (int k0 = 0; k0 < 128; k0 += 16) {
    __syncthreads();
    if constexpr (PANEL_T) {   // Pan[kk][x] = cc[x][k0+kk]
#pragma unroll
      for (int rep = 0; rep < 2; ++rep) {
        int xx = (tid >> 2) + rep * 64;
        int kk4 = (tid & 3) << 2;
        float4 v = *(const float4*)&cc[xx * 128 + k0 + kk4];
        Pan[(kk4 + 0) * 132 + xx] = v.x;
        Pan[(kk4 + 1) * 132 + xx] = v.y;
        Pan[(kk4 + 2) * 132 + xx] = v.z;
        Pan[(kk4 + 3) * 132 + xx] = v.w;
      }
    } else {                   // Pan[kk][x] = cc[k0+kk][x]
#pragma unroll
      for (int rep = 0; rep < 2; ++rep) {
        int q = tid + rep * 256;
        int kk = q >> 5, c4 = (q & 31) << 2;
        *(float4*)&Pan[kk * 132 + c4] = *(const float4*)&cc[(k0 + kk) * 128 + c4];
      }
    }
    __syncthreads();
#pragma unroll
    for (int kk = 0; kk < 16; ++kk) {
      const int k = k0 + kk;
      float a[8], bv[8];
      if constexpr (A_PANEL) {
        *(float4*)&a[0] = *(const float4*)&Pan[kk * 132 + i0];
        *(float4*)&a[4] = *(const float4*)&Pan[kk * 132 + i0 + 4];
        *(float4*)&bv[0] = *(const float4*)&Bfull[swz4(k, j0)];
        *(float4*)&bv[4] = *(const float4*)&Bfull[swz4(k, j0 + 4)];
      } else {
        *(float4*)&a[0] = *(const float4*)&Afull[swz4(k, i0)];
        *(float4*)&a[4] = *(const float4*)&Afull[swz4(k, i0 + 4)];
        *(float4*)&bv[0] = *(const float4*)&Pan[kk * 132 + j0];
        *(float4*)&bv[4] = *(const float4*)&Pan[kk * 132 + j0 + 4];
      }
#pragma unroll
      for (int i = 0; i < 8; ++i)
#pragma unroll
        for (int j = 0; j < 8; ++j) acc[i][j] = fmaf(a[i], bv[j], acc[i][j]);
    }
  }
  if constexpr (OUT_T) {
#pragma unroll
    for (int j = 0; j < 8; ++j) {
      *(float4*)&OUT[swz4(j0 + j, i0)] =
          make_float4(acc[0][j], acc[1][j], acc[2][j], acc[3][j]);
      *(float4*)&OUT[swz4(j0 + j, i0 + 4)] =
          make_float4(acc[4][j], acc[5][j], acc[6][j], acc[7][j]);
    }
  } else {
#pragma unroll
    for (int i = 0; i < 8; ++i) {
      *(float4*)&OUT[swz4(i0 + i, j0)] =
          make_float4(acc[i][0], acc[i][1], acc[i][2], acc[i][3]);
      *(float4*)&OUT[swz4(i0 + i, j0 + 4)] =
          make_float4(acc[i][4], acc[i][5], acc[i][6], acc[i][7]);
    }
  }
}

__global__ __launch_bounds__(256) void heat_kernel(
    float* bufA, float* bufB, const float* __restrict__ P,
    const float* __restrict__ cc, int Ceff) {
  __shared__ float Xs[128 * 128];
  __shared__ float Ys[128 * 128];
  __shared__ float Pan[16 * 132];
  int tid = threadIdx.x;
  int plane = blockIdx.x;
  int b = plane / Ceff, c = plane % Ceff;
  float* Ug = (c < 96) ? (bufA + (size_t)(b * 96 + c) * HW)
                       : (bufB + (size_t)(b * 96 + (c - 96)) * HW);
  const float* Pp = P + (size_t)c * HW;

#pragma unroll
  for (int t = 0; t < 16; ++t) {           // load U (swizzled into Xs)
    int q = tid + t * 256;                 // float4 index, 4096 total
    int r = q >> 5, c4 = (q & 31) << 2;
    *(float4*)&Xs[swz4(r, c4)] = *(const float4*)&Ug[(r << 7) + c4];
  }
  // step1: T = Cc*U        (A = panelT, B = Xs)  -> Ys holds T^T
  mm_step<true, true, true>(cc, nullptr, Xs, Pan, Ys, tid);
  // step2: S = T*Cc^T      (A = Ys(T^T), B = panelT) -> Xs holds S
  mm_step<false, true, false>(cc, Ys, nullptr, Pan, Xs, tid);
  __syncthreads();
#pragma unroll
  for (int t = 0; t < 64; ++t) {           // decay multiply S *= P
    int q = tid + t * 256;
    int r = q >> 7, cx = q & 127;
    int idx = (r << 7) + (((((cx >> 2) ^ ((r >> 3) & 7)) << 2)) | (cx & 3));
    Xs[idx] *= Pp[q];
  }
  // step3: T2 = Cc^T*S     (A = panelR, B = Xs) -> Ys holds T2^T
  mm_step<true, false, true>(cc, nullptr, Xs, Pan, Ys, tid);
  // step4: Y = T2*Cc       (A = Ys(T2^T), B = panelR) -> Xs holds Y
  mm_step<false, false, false>(cc, Ys, nullptr, Pan, Xs, tid);
  __syncthreads();
#pragma unroll
  for (int t = 0; t < 16; ++t) {           // store in place
    int q = tid + t * 256;
    int r = q >> 5, c4 = (q & 31) << 2;
    *(float4*)&Ug[(r << 7) + c4] = *(float4*)&Xs[swz4(r, c4)];
  }
}

// ---------- K5: catmean lower half = mean_b(y1) ----------
__global__ void k5_mean(const float* __restrict__ x1p, float* __restrict__ cmL) {
  int idx = blockIdx.x * 256 + threadIdx.x;   // < 96*HW, layout [c][s]
  int c = idx >> 14, s = idx & 16383;
  float sum = 0.f;
#pragma unroll
  for (int b = 0; b < 8; ++b) sum += x1p[(size_t)(b * 96 + c) * HW + s];
  cmL[idx] = sum * 0.125f;
}

// ---------- K6: skfeat = catmean @ lin2_w^T + lin2_b (c-major in/out) ----------
__global__ __launch_bounds__(256) void k6_skf(
    const float* __restrict__ cm, const float* __restrict__ w2T,
    const float* __restrict__ b2, float* __restrict__ skf) {
  int row = blockIdx.x * 256 + threadIdx.x;
  for (int half = 0; half < 2; ++half) {
    float acc[96];
#pragma unroll
    for (int d = 0; d < 96; ++d) acc[d] = b2[half * 96 + d];
    for (int k = 0; k < 192; ++k) {
      float a = cm[(size_t)k * HW + row];
      const float* wr = w2T + k * 192 + half * 96;
#pragma unroll
      for (int d = 0; d < 96; ++d) acc[d] = fmaf(a, wr[d], acc[d]);
    }
#pragma unroll
    for (int d = 0; d < 96; ++d) skf[(size_t)(half * 96 + d) * HW + row] = acc[d];
  }
}

// ---------- K7: k2 = relu(skf@k2_w^T + k2_b); P2 = exp(-e*k2) ----------
__global__ __launch_bounds__(256) void k7_k2(
    const float* __restrict__ skf, const float* __restrict__ w2T,
    const float* __restrict__ b2, const float* __restrict__ ee,
    float* __restrict__ P2) {
  int row = blockIdx.x * 256 + threadIdx.x;
  float er = ee[row];
  for (int half = 0; half < 2; ++half) {
    float acc[96];
#pragma unroll
    for (int d = 0; d < 96; ++d) acc[d] = b2[half * 96 + d];
    for (int k = 0; k < 192; ++k) {
      float a = skf[(size_t)k * HW + row];
      const float* wr = w2T + k * 192 + half * 96;
#pragma unroll
      for (int d = 0; d < 96; ++d) acc[d] = fmaf(a, wr[d], acc[d]);
    }
#pragma unroll
    for (int d = 0; d < 96; ++d)
      P2[(size_t)(half * 96 + d) * HW + row] = expf(-er * fmaxf(acc[d], 0.f));
  }
}

// ---------- K9: lin3 + LayerNorm + *silu(z) + out GEMM + NCHW write ----------
__global__ __launch_bounds__(256) void k9_epilogue(
    const float* __restrict__ y1, const float* __restrict__ y2,
    const float* __restrict__ z,
    const float* __restrict__ lin3T, const float* __restrict__ lin3b,
    const float* __restrict__ lng, const float* __restrict__ lnb,
    const float* __restrict__ outT, const float* __restrict__ outb,
    float* __restrict__ out) {
  int gid = blockIdx.x * 256 + threadIdx.x;
  int b = gid >> 14, hw = gid & 16383;
  float t[96];
#pragma unroll
  for (int d = 0; d < 96; ++d) t[d] = lin3b[d];
  for (int k = 0; k < 96; ++k) {
    float a = y1[(size_t)(b * 96 + k) * HW + hw];
    const float* wr = lin3T + k * 96;
#pragma unroll
    for (int d = 0; d < 96; ++d) t[d] = fmaf(a, wr[d], t[d]);
  }
  for (int k = 0; k < 96; ++k) {
    float a = y2[(size_t)(b * 96 + k) * HW + hw];
    const float* wr = lin3T + (96 + k) * 96;
#pragma unroll
    for (int d = 0; d < 96; ++d) t[d] = fmaf(a, wr[d], t[d]);
  }
  float mu = 0.f;
#pragma unroll
  for (int d = 0; d < 96; ++d) mu += t[d];
  mu *= (1.f / 96.f);
  float var = 0.f;
#pragma unroll
  for (int d = 0; d < 96; ++d) { float dv = t[d] - mu; var = fmaf(dv, dv, var); }
  var *= (1.f / 96.f);
  float inv = rsqrtf(var + 1e-5f);
  const float* zp = z + (size_t)gid * 96;
#pragma unroll
  for (int d = 0; d < 96; ++d) {
    float zv = zp[d];
    float sil = zv / (1.f + expf(-zv));
    t[d] = ((t[d] - mu) * inv * lng[d] + lnb[d]) * sil;
  }
  for (int half = 0; half < 2; ++half) {
    float acc[48];
#pragma unroll
    for (int j = 0; j < 48; ++j) acc[j] = outb[half * 48 + j];
#pragma unroll
    for (int c2 = 0; c2 < 96; ++c2) {
      float a = t[c2];
      const float* wr = outT + c2 * 96 + half * 48;
#pragma unroll
      for (int j = 0; j < 48; ++j) acc[j] = fmaf(a, wr[j], acc[j]);
    }
#pragma unroll
    for (int j = 0; j < 48; ++j)
      out[(size_t)(b * 96 + half * 48 + j) * HW + hw] = acc[j];
  }
}

extern "C" void kernel_launch(void* const* d_in, const int* in_sizes, int n_in,
                              void* d_out, int out_size, void* d_ws, size_t ws_size,
                              hipStream_t stream) {
  const float* x      = (const float*)d_in[0];
  const float* fe     = (const float*)d_in[1];
  const float* of     = (const float*)d_in[2];
  const float* dw_w   = (const float*)d_in[3];
  const float* dw_b   = (const float*)d_in[4];
  const float* lin_w  = (const float*)d_in[5];
  const float* lin_b  = (const float*)d_in[6];
  const float* k_w    = (const float*)d_in[7];
  const float* k_b    = (const float*)d_in[8];
  const float* lin2_w = (const float*)d_in[9];
  const float* lin2_b = (const float*)d_in[10];
  const float* k2_w   = (const float*)d_in[11];
  const float* k2_b   = (const float*)d_in[12];
  const float* lin3_w = (const float*)d_in[13];
  const float* lin3_b = (const float*)d_in[14];
  const float* ln_g   = (const float*)d_in[15];
  const float* ln_b   = (const float*)d_in[16];
  const float* out_w  = (const float*)d_in[17];
  const float* out_b  = (const float*)d_in[18];
  float* out = (float*)d_out;

  float* ws    = (float*)d_ws;
  float* x1p   = ws;                      // [B][96][HW]  (x1 -> y1 -> y2 low)
  float* z     = x1p   + 12582912;        // [B][HW][96]
  float* ofp   = z     + 12582912;        // [B][96][HW]  (outline planes -> y2 high)
  float* cm    = ofp   + 12582912;        // [192][HW] catmean (c-major)
  float* skf   = cm    + 3145728;         // [192][HW]
  float* P1    = skf   + 3145728;         // [96][HW]
  float* P2    = P1    + 1572864;         // [192][HW]
  float* cc    = P2    + 3145728;         // [128][128]
  float* ee    = cc    + 16384;           // [128][128]
  float* linT  = ee    + 16384;           // [96][192]
  float* kT    = linT  + 18432;           // [96][96]
  float* lin2T = kT    + 9216;            // [192][192]
  float* k2T   = lin2T + 36864;           // [192][192]
  float* lin3T = k2T   + 36864;           // [192][96]
  float* outT  = lin3T + 18432;           // [96][96]
  (void)in_sizes; (void)n_in; (void)out_size; (void)ws_size;

  k0_tables<<<64, 256, 0, stream>>>(cc, ee);
  k_wt<<<72, 256, 0, stream>>>(lin_w, linT, 192, 96);
  k_wt<<<36, 256, 0, stream>>>(k_w, kT, 96, 96);
  k_wt<<<144, 256, 0, stream>>>(lin2_w, lin2T, 192, 192);
  k_wt<<<144, 256, 0, stream>>>(k2_w, k2T, 192, 192);
  k_wt<<<72, 256, 0, stream>>>(lin3_w, lin3T, 96, 192);
  k_wt<<<36, 256, 0, stream>>>(out_w, outT, 96, 96);

  k2_conv_lin<<<512, 256, 0, stream>>>(x, dw_w, dw_b, linT, lin_b, x1p, z);
  k3_transpose_mean<<<256, 256, 0, stream>>>(of, ofp, cm + (size_t)96 * HW);
  k3b_kgemm<<<64, 256, 0, stream>>>(fe, cm + (size_t)96 * HW, kT, k_b, ee, P1);
  heat_kernel<<<768, 256, 0, stream>>>(x1p, x1p, P1, cc, 96);
  k5_mean<<<6144, 256, 0, stream>>>(x1p, cm);
  k6_skf<<<64, 256, 0, stream>>>(cm, lin2T, lin2_b, skf);
  k7_k2<<<64, 256, 0, stream>>>(skf, k2T, k2_b, ee, P2);
  heat_kernel<<<1536, 256, 0, stream>>>(x1p, ofp, P2, cc, 192);
  k9_epilogue<<<512, 256, 0, stream>>>(x1p, ofp, z, lin3T, lin3_b, ln_g, ln_b,
                                       outT, out_b, out);
}